// Round 12
// baseline (499.384 us; speedup 1.0000x reference)
//
#include <hip/hip_runtime.h>
#include <hip/hip_fp16.h>

// ---------------------------------------------------------------------------
// GENConv GNN forward. Round 11 == Round 10 resubmit (prior bench hit a GPU
// acquisition timeout; no counters were produced).
//  - conv: eps-free message math (exact to 1e-7), pre-multiplied byte offsets
//    for gathers, 8/4/1-wide unrolled loop (8 independent gather chains).
//  - bnfin: 16-block parallel partial reduction (was 1 block).
// Rest carried from round 9 (497 us, passing).
// ---------------------------------------------------------------------------

#define HH 128   // hidden
#define H2 256   // 2*hidden
#define MMP 256  // persistent mm1 x-grid

typedef __attribute__((ext_vector_type(8))) short short8v;
typedef __attribute__((ext_vector_type(4))) float f32x4;
typedef __attribute__((ext_vector_type(2))) float f32x2;

__device__ __forceinline__ short f2bf(float f) {
  union { float f; unsigned u; } v; v.f = f;
  unsigned r = v.u + 0x7fff + ((v.u >> 16) & 1);  // round-to-nearest-even
  return (short)(r >> 16);
}
__device__ __forceinline__ float bf2f(ushort s) {
  union { unsigned u; float f; } v; v.u = ((unsigned)s) << 16;
  return v.f;
}
__device__ __forceinline__ f32x2 splat2(float s) { return (f32x2){s, s}; }

// ---- node encoder: h16 = fp16(x @ wn + bn)   (x: [N,6], wn: [6,128]) ----
__global__ void k_encode(const float* __restrict__ x, const float* __restrict__ wn,
                         const float* __restrict__ bnb, __half* __restrict__ h16, int n) {
  int c = threadIdx.x & 127;
  int node = blockIdx.x * 2 + (threadIdx.x >> 7);
  if (node >= n) return;
  const float* xr = x + (size_t)node * 6;
  float acc = bnb[c];
#pragma unroll
  for (int k = 0; k < 6; ++k) acc = fmaf(xr[k], wn[k * HH + c], acc);
  h16[(size_t)node * HH + c] = __float2half(acc);
}

// ---- CSR build: dst histogram, capturing per-edge rank within bucket ----
__global__ void k_hist(const int* __restrict__ dst, int* __restrict__ counts,
                       int* __restrict__ rank, int E) {
  int e = blockIdx.x * 256 + threadIdx.x;
  if (e < E) rank[e] = atomicAdd(&counts[dst[e]], 1);
}

// ---- per-graph node counts via binary search on sorted batch ----
__global__ __launch_bounds__(1024) void k_cntg(const int* __restrict__ batch,
                                               float* __restrict__ cntf, int n, int G) {
  __shared__ int lb[513];
  int t = threadIdx.x;
  for (int v = t; v <= G; v += 1024) {
    int lo = 0, hi = n;
    while (lo < hi) {
      int mid = (lo + hi) >> 1;
      if (batch[mid] < v) lo = mid + 1; else hi = mid;
    }
    lb[v] = lo;
  }
  __syncthreads();
  for (int g = t; g < G; g += 1024) cntf[g] = (float)(lb[g + 1] - lb[g]);
}

// single-block exclusive scan, 4 elements/thread per pass (int4)
__global__ void k_scan(const int* __restrict__ counts, int* __restrict__ rowptr, int n) {
  __shared__ int wsum[16];
  __shared__ int carry;
  int t = threadIdx.x;
  int lane = t & 63, w = t >> 6;
  if (t == 0) carry = 0;
  __syncthreads();
  for (int base = 0; base < n; base += 4096) {
    int idx = base + t * 4;
    int4 v = make_int4(0, 0, 0, 0);
    if (idx + 3 < n) {
      v = *(const int4*)(counts + idx);
    } else {
      if (idx < n)     v.x = counts[idx];
      if (idx + 1 < n) v.y = counts[idx + 1];
      if (idx + 2 < n) v.z = counts[idx + 2];
    }
    int tsum = v.x + v.y + v.z + v.w;
    int x = tsum;
#pragma unroll
    for (int d = 1; d < 64; d <<= 1) {
      int y = __shfl_up(x, d);
      if (lane >= d) x += y;
    }
    if (lane == 63) wsum[w] = x;
    __syncthreads();
    if (w == 0 && lane < 16) {
      int s = wsum[lane];
#pragma unroll
      for (int d = 1; d < 16; d <<= 1) {
        int y = __shfl_up(s, d);
        if (lane >= d) s += y;
      }
      wsum[lane] = s;
    }
    __syncthreads();
    int waveoff = (w == 0) ? 0 : wsum[w - 1];
    int c0 = carry;
    int excl = c0 + waveoff + x - tsum;
    int4 o;
    o.x = excl;
    o.y = excl + v.x;
    o.z = o.y + v.y;
    o.w = o.z + v.z;
    if (idx + 3 < n) {
      *(int4*)(rowptr + idx) = o;
    } else {
      if (idx < n)     rowptr[idx] = o.x;
      if (idx + 1 < n) rowptr[idx + 1] = o.y;
      if (idx + 2 < n) rowptr[idx + 2] = o.z;
    }
    __syncthreads();
    if (t == 0) carry = c0 + wsum[15];
    __syncthreads();
  }
  if (t == 0) rowptr[n] = carry;
}

// scatter edges into CSR order (atomic-free). soff stores BYTE offsets of
// source rows (src*HH*2 = src<<8) so conv gathers need no shift.
__global__ void k_fill(const int* __restrict__ src, const int* __restrict__ dst,
                       const float4* __restrict__ eattr,
                       const int* __restrict__ rowptr, const int* __restrict__ rank,
                       int* __restrict__ soff, float4* __restrict__ eattrs, int E) {
  int e = blockIdx.x * 256 + threadIdx.x;
  if (e >= E) return;
  int pos = rowptr[dst[e]] + rank[e];
  soff[pos] = src[e] << 8;
  eattrs[pos] = eattr[e];
}

// ---- GENConv message + softmax aggregation over CSR ----
// one wave per dst node; lane = 2 channels, packed-fp32 math.
// eps-free: m = relu(h+e); softmax ratio differs from reference by <=1e-7.
// 8-wide -> 4-wide -> 1-wide loop: up to 8 independent gather chains.
__global__ __launch_bounds__(256) void k_conv(
    const __half* __restrict__ h16, const float4* __restrict__ eattrs,
    const float* __restrict__ we, const float* __restrict__ be,
    const int* __restrict__ rowptr, const int* __restrict__ soff,
    ushort* __restrict__ hresb, int n) {
  int d = blockIdx.x * 4 + (threadIdx.x >> 6);
  if (d >= n) return;
  int lane = threadIdx.x & 63;
  int c0 = lane * 2;
  f32x2 W0 = *(const f32x2*)(we + c0);
  f32x2 W1 = *(const f32x2*)(we + 128 + c0);
  f32x2 W2 = *(const f32x2*)(we + 256 + c0);
  f32x2 W3 = *(const f32x2*)(we + 384 + c0);
  f32x2 BE = *(const f32x2*)(be + c0);
  const f32x2 ZERO = splat2(0.f);
  const char* hb = (const char*)h16 + (size_t)(lane * 4);
  int p0 = rowptr[d], p1 = rowptr[d + 1];
  f32x2 Sab = ZERO, Wab = ZERO, Scd = ZERO, Wcd = ZERO;

  auto edge = [&](float4 a, __half2 h2, f32x2& S, f32x2& Wm) {
    float2 hf = __half22float2(h2);
    f32x2 e = W0 * splat2(a.x) + (W1 * splat2(a.y) + (W2 * splat2(a.z) + (W3 * splat2(a.w) + BE)));
    f32x2 m = __builtin_elementwise_max((f32x2){hf.x, hf.y} + e, ZERO);
    f32x2 xe = (f32x2){__expf(m.x), __expf(m.y)};
    S += xe;
    Wm += m * xe;
  };

  int p = p0;
  for (; p + 8 <= p1; p += 8) {
    int o0 = soff[p],     o1 = soff[p + 1], o2 = soff[p + 2], o3 = soff[p + 3];
    int o4 = soff[p + 4], o5 = soff[p + 5], o6 = soff[p + 6], o7 = soff[p + 7];
    float4 a0 = eattrs[p],     a1 = eattrs[p + 1], a2 = eattrs[p + 2], a3 = eattrs[p + 3];
    float4 a4 = eattrs[p + 4], a5 = eattrs[p + 5], a6 = eattrs[p + 6], a7 = eattrs[p + 7];
    __half2 h0 = *(const __half2*)(hb + o0);
    __half2 h1 = *(const __half2*)(hb + o1);
    __half2 h2 = *(const __half2*)(hb + o2);
    __half2 h3 = *(const __half2*)(hb + o3);
    __half2 h4 = *(const __half2*)(hb + o4);
    __half2 h5 = *(const __half2*)(hb + o5);
    __half2 h6 = *(const __half2*)(hb + o6);
    __half2 h7 = *(const __half2*)(hb + o7);
    edge(a0, h0, Sab, Wab); edge(a1, h1, Sab, Wab);
    edge(a2, h2, Scd, Wcd); edge(a3, h3, Scd, Wcd);
    edge(a4, h4, Sab, Wab); edge(a5, h5, Sab, Wab);
    edge(a6, h6, Scd, Wcd); edge(a7, h7, Scd, Wcd);
  }
  for (; p + 4 <= p1; p += 4) {
    int o0 = soff[p], o1 = soff[p + 1], o2 = soff[p + 2], o3 = soff[p + 3];
    float4 a0 = eattrs[p], a1 = eattrs[p + 1], a2 = eattrs[p + 2], a3 = eattrs[p + 3];
    __half2 h0 = *(const __half2*)(hb + o0);
    __half2 h1 = *(const __half2*)(hb + o1);
    __half2 h2 = *(const __half2*)(hb + o2);
    __half2 h3 = *(const __half2*)(hb + o3);
    edge(a0, h0, Sab, Wab); edge(a1, h1, Sab, Wab);
    edge(a2, h2, Scd, Wcd); edge(a3, h3, Scd, Wcd);
  }
  for (; p < p1; ++p) {
    int o = soff[p];
    float4 a = eattrs[p];
    __half2 h2 = *(const __half2*)(hb + o);
    edge(a, h2, Sab, Wab);
  }
  f32x2 S = Sab + Scd, W = Wab + Wcd;
  __half2 hd2 = *(const __half2*)(h16 + (size_t)d * HH + c0);
  float2 hd = __half22float2(hd2);
  float r0 = W.x / (S.x + 1e-16f) + hd.x;
  float r1 = W.y / (S.y + 1e-16f) + hd.y;
  ushort2 o;
  o.x = (ushort)f2bf(r0);
  o.y = (ushort)f2bf(r1);
  *(ushort2*)(hresb + (size_t)d * HH + c0) = o;
}

// ---- weight pre-convert: fp32 [K][Ncols] -> bf16 fragment-major ----
__global__ void k_wconv(const float* __restrict__ W, short* __restrict__ out,
                        int logn, int K) {
  int layer = blockIdx.y;
  int total = K << logn;
  int e = blockIdx.x * 256 + threadIdx.x;
  if (e >= total) return;
  const float* Wl = W + (size_t)layer * total;
  short* ol = out + (size_t)layer * total;
  int k = e >> logn, col = e & ((1 << logn) - 1);
  int ty = col >> 7, colL = col & 127;
  int wc = colL >> 6, n = (colL >> 4) & 3, l15 = colL & 15;
  int kc = k >> 7, kl = k & 127;
  int ksl = kl >> 5, lhi = (kl >> 3) & 3, j = kl & 7;
  int KC = K >> 7;
  size_t idx = (size_t)(ty * KC + kc) * 16384 +
               ((((wc * 4 + n) * 4 + ksl) * 64 + lhi * 16 + l15) * 8 + j);
  ol[idx] = f2bf(Wl[e]);
}

// ---- mm1 (MFMA, persistent): h1b = bf16(hresb @ w1 + b1), BN partials ----
__global__ __launch_bounds__(256) void k_mm1p(
    const ushort* __restrict__ Ab, const short* __restrict__ Bf,
    const float* __restrict__ bias, ushort* __restrict__ Cb,
    float* __restrict__ partial, int M, int mtiles) {
  __shared__ float red[256];
  int t = threadIdx.x;
  int bx = blockIdx.x, ty = blockIdx.y;
  int lane = t & 63, w = t >> 6;
  int wr = w >> 1, wc = w & 1;
  int l15 = lane & 15, lhi = lane >> 4;
  const short* Bt = Bf + (size_t)ty * 16384;
  short8v breg[4][4];
#pragma unroll
  for (int n = 0; n < 4; ++n)
#pragma unroll
    for (int ksl = 0; ksl < 4; ++ksl)
      breg[n][ksl] = *(const short8v*)(Bt + ((((wc * 4 + n) * 4 + ksl) * 64 + lane) * 8));
  float bb[4];
#pragma unroll
  for (int n = 0; n < 4; ++n) bb[n] = bias[ty * 128 + wc * 64 + n * 16 + l15];
  float cs[4] = {0.f, 0.f, 0.f, 0.f}, cq[4] = {0.f, 0.f, 0.f, 0.f};

  short8v a_cur[2][4], a_nxt[2][4];
  int tile = bx;
  if (tile < mtiles) {
    int row0 = tile * 64;
#pragma unroll
    for (int m = 0; m < 2; ++m) {
      int grow = row0 + (wr * 2 + m) * 16 + l15;
      if (grow < M) {
        const ushort* ap = Ab + (size_t)grow * HH + lhi * 8;
#pragma unroll
        for (int ksl = 0; ksl < 4; ++ksl) a_cur[m][ksl] = *(const short8v*)(ap + ksl * 32);
      } else {
#pragma unroll
        for (int ksl = 0; ksl < 4; ++ksl) a_cur[m][ksl] = (short8v){0,0,0,0,0,0,0,0};
      }
    }
  }
#pragma unroll 1
  for (; tile < mtiles; tile += MMP) {
    int nt = tile + MMP;
    if (nt < mtiles) {
      int row0n = nt * 64;
#pragma unroll
      for (int m = 0; m < 2; ++m) {
        int grow = row0n + (wr * 2 + m) * 16 + l15;
        if (grow < M) {
          const ushort* ap = Ab + (size_t)grow * HH + lhi * 8;
#pragma unroll
          for (int ksl = 0; ksl < 4; ++ksl) a_nxt[m][ksl] = *(const short8v*)(ap + ksl * 32);
        } else {
#pragma unroll
          for (int ksl = 0; ksl < 4; ++ksl) a_nxt[m][ksl] = (short8v){0,0,0,0,0,0,0,0};
        }
      }
    }
    f32x4 acc[2][4];
#pragma unroll
    for (int m = 0; m < 2; ++m)
#pragma unroll
      for (int n = 0; n < 4; ++n) acc[m][n] = (f32x4){0.f, 0.f, 0.f, 0.f};
#pragma unroll
    for (int ksl = 0; ksl < 4; ++ksl)
#pragma unroll
      for (int m = 0; m < 2; ++m)
#pragma unroll
        for (int n = 0; n < 4; ++n)
          acc[m][n] = __builtin_amdgcn_mfma_f32_16x16x32_bf16(a_cur[m][ksl], breg[n][ksl],
                                                              acc[m][n], 0, 0, 0);
    int row0 = tile * 64;
#pragma unroll
    for (int n = 0; n < 4; ++n) {
      int colL = wc * 64 + n * 16 + l15;
#pragma unroll
      for (int m = 0; m < 2; ++m) {
        int rbase = row0 + wr * 32 + m * 16 + lhi * 4;
#pragma unroll
        for (int r = 0; r < 4; ++r) {
          int row = rbase + r;
          if (row < M) {
            float o = acc[m][n][r] + bb[n];
            Cb[(size_t)row * H2 + ty * 128 + colL] = (ushort)f2bf(o);
            cs[n] += o; cq[n] += o * o;
          }
        }
      }
    }
#pragma unroll
    for (int m = 0; m < 2; ++m)
#pragma unroll
      for (int ksl = 0; ksl < 4; ++ksl) a_cur[m][ksl] = a_nxt[m][ksl];
  }
  red[t] = 0.f;
  __syncthreads();
#pragma unroll
  for (int n = 0; n < 4; ++n) {
    int colL = wc * 64 + n * 16 + l15;
    atomicAdd(&red[colL], cs[n]);
    atomicAdd(&red[128 + colL], cq[n]);
  }
  __syncthreads();
  partial[((size_t)(ty * MMP + bx)) * 256 + t] = red[t];
}

// ---- reduce partials, fold BN stats (parallel: 16 blocks x 16 channels) ----
__global__ __launch_bounds__(256) void k_bnfin(
    const float* __restrict__ partial, const float* __restrict__ g,
    const float* __restrict__ bt, float* __restrict__ scale,
    float* __restrict__ shift, float invN) {
  __shared__ float shs[256], shq[256];
  int t = threadIdx.x;
  int b = blockIdx.x;          // 0..15
  int ty = b >> 3;             // 0..1
  int col0 = (b & 7) * 16;     // 0..112
  int ch = t & 15;             // channel within group
  int seg = t >> 4;            // 0..15 (each covers 16 partial blocks)
  int colL = col0 + ch;
  const float* base = partial + (size_t)ty * MMP * 256;
  float s = 0.f, q = 0.f;
#pragma unroll 4
  for (int bx = seg * 16; bx < seg * 16 + 16; ++bx) {
    s += base[(size_t)bx * 256 + colL];
    q += base[(size_t)bx * 256 + 128 + colL];
  }
  shs[t] = s; shq[t] = q;
  __syncthreads();
  if (t < 16) {
    float ss = 0.f, qq = 0.f;
#pragma unroll
    for (int sg = 0; sg < 16; ++sg) {
      ss += shs[sg * 16 + t];
      qq += shq[sg * 16 + t];
    }
    int cg = ty * 128 + col0 + t;
    float mu = ss * invN;
    float var = qq * invN - mu * mu;
    float rs = rsqrtf(var + 1e-5f);
    float sc = rs * g[cg];
    scale[cg] = sc;
    shift[cg] = bt[cg] - mu * sc;
  }
}

// ---- mm2 (MFMA): h16 = fp16( relu( relu(h1b*sc+sh) @ w2 + b2 ) ) ----
__global__ __launch_bounds__(256) void k_mm2f(
    const ushort* __restrict__ Ab, const short* __restrict__ Bf,
    const float* __restrict__ bias, const float* __restrict__ scale,
    const float* __restrict__ shift, __half* __restrict__ h16, int M) {
  int t = threadIdx.x;
  int row0 = blockIdx.x * 64;
  int lane = t & 63, w = t >> 6;
  int wr = w >> 1, wc = w & 1;
  int l15 = lane & 15, lhi = lane >> 4;
  int grow[2]; bool gv[2];
#pragma unroll
  for (int m = 0; m < 2; ++m) {
    grow[m] = row0 + (wr * 2 + m) * 16 + l15;
    gv[m] = grow[m] < M;
  }
  f32x4 acc[2][4];
#pragma unroll
  for (int m = 0; m < 2; ++m)
#pragma unroll
    for (int n = 0; n < 4; ++n) acc[m][n] = (f32x4){0.f, 0.f, 0.f, 0.f};
#pragma unroll 1
  for (int kc = 0; kc < 2; ++kc) {
    const short* Bk = Bf + (size_t)kc * 16384;
    short8v breg[4][4];
#pragma unroll
    for (int n = 0; n < 4; ++n)
#pragma unroll
      for (int ksl = 0; ksl < 4; ++ksl)
        breg[n][ksl] = *(const short8v*)(Bk + ((((wc * 4 + n) * 4 + ksl) * 64 + lane) * 8));
#pragma unroll
    for (int ksl = 0; ksl < 4; ++ksl) {
      int kb = kc * 128 + (ksl * 4 + lhi) * 8;
      float4 sc0 = *(const float4*)(scale + kb);
      float4 sc1 = *(const float4*)(scale + kb + 4);
      float4 sh0 = *(const float4*)(shift + kb);
      float4 sh1 = *(const float4*)(shift + kb + 4);
      short8v av[2];
#pragma unroll
      for (int m = 0; m < 2; ++m) {
        if (gv[m]) {
          short8v raw = *(const short8v*)(Ab + (size_t)grow[m] * H2 + kb);
          float f;
          f = fmaxf(fmaf(bf2f((ushort)raw[0]), sc0.x, sh0.x), 0.f); av[m][0] = f2bf(f);
          f = fmaxf(fmaf(bf2f((ushort)raw[1]), sc0.y, sh0.y), 0.f); av[m][1] = f2bf(f);
          f = fmaxf(fmaf(bf2f((ushort)raw[2]), sc0.z, sh0.z), 0.f); av[m][2] = f2bf(f);
          f = fmaxf(fmaf(bf2f((ushort)raw[3]), sc0.w, sh0.w), 0.f); av[m][3] = f2bf(f);
          f = fmaxf(fmaf(bf2f((ushort)raw[4]), sc1.x, sh1.x), 0.f); av[m][4] = f2bf(f);
          f = fmaxf(fmaf(bf2f((ushort)raw[5]), sc1.y, sh1.y), 0.f); av[m][5] = f2bf(f);
          f = fmaxf(fmaf(bf2f((ushort)raw[6]), sc1.z, sh1.z), 0.f); av[m][6] = f2bf(f);
          f = fmaxf(fmaf(bf2f((ushort)raw[7]), sc1.w, sh1.w), 0.f); av[m][7] = f2bf(f);
        } else {
          av[m] = (short8v){0,0,0,0,0,0,0,0};
        }
      }
#pragma unroll
      for (int m = 0; m < 2; ++m)
#pragma unroll
        for (int n = 0; n < 4; ++n)
          acc[m][n] = __builtin_amdgcn_mfma_f32_16x16x32_bf16(av[m], breg[n][ksl],
                                                              acc[m][n], 0, 0, 0);
    }
  }
#pragma unroll
  for (int n = 0; n < 4; ++n) {
    int colL = wc * 64 + n * 16 + l15;
    float bb = bias[colL];
#pragma unroll
    for (int m = 0; m < 2; ++m) {
      int rbase = row0 + wr * 32 + m * 16 + lhi * 4;
#pragma unroll
      for (int r = 0; r < 4; ++r) {
        int row = rbase + r;
        if (row < M)
          h16[(size_t)row * HH + colL] = __float2half(fmaxf(acc[m][n][r] + bb, 0.f));
      }
    }
  }
}

// ---- mean-pool partial sums (batch sorted -> run-length accumulate) ----
__global__ __launch_bounds__(128) void k_pool(const __half* __restrict__ h16,
                                              const int* __restrict__ batch,
                                              float* __restrict__ pool, int n) {
  int c = threadIdx.x;
  int n0 = blockIdx.x * 64;
  int nend = min(n0 + 64, n);
  float acc = 0.f;
  int gprev = batch[n0];
  for (int i = n0; i < nend; ++i) {
    int g = batch[i];
    if (g != gprev) {
      atomicAdd(&pool[(size_t)gprev * HH + c], acc);
      acc = 0.f;
      gprev = g;
    }
    acc += __half2float(h16[(size_t)i * HH + c]);
  }
  atomicAdd(&pool[(size_t)gprev * HH + c], acc);
}

// ---- final: sigmoid(mean_pool @ wd + bd) ----
__global__ __launch_bounds__(64) void k_final(const float* __restrict__ pool,
                                              const float* __restrict__ cntf,
                                              const float* __restrict__ wd,
                                              const float* __restrict__ bd,
                                              float* __restrict__ out) {
  int g = blockIdx.x;
  int t = threadIdx.x;
  float inv = 1.f / fmaxf(cntf[g], 1.f);
  float v = pool[(size_t)g * HH + t] * inv * wd[t] +
            pool[(size_t)g * HH + 64 + t] * inv * wd[64 + t];
#pragma unroll
  for (int d = 32; d; d >>= 1) v += __shfl_down(v, d);
  if (t == 0) out[g] = 1.f / (1.f + __expf(-(v + bd[0])));
}

// ---------------------------------------------------------------------------
extern "C" void kernel_launch(void* const* d_in, const int* in_sizes, int n_in,
                              void* d_out, int out_size, void* d_ws, size_t ws_size,
                              hipStream_t stream) {
  const float* x     = (const float*)d_in[0];
  const float* eattr = (const float*)d_in[1];
  const int*   eidx  = (const int*)d_in[2];
  const int*   batch = (const int*)d_in[3];
  const float* wn    = (const float*)d_in[4];
  const float* bnb   = (const float*)d_in[5];
  const float* we    = (const float*)d_in[6];
  const float* be    = (const float*)d_in[7];
  const float* cw1   = (const float*)d_in[8];
  const float* cb1   = (const float*)d_in[9];
  const float* cg    = (const float*)d_in[10];
  const float* cbt   = (const float*)d_in[11];
  const float* cw2   = (const float*)d_in[12];
  const float* cb2   = (const float*)d_in[13];
  const float* wd    = (const float*)d_in[14];
  const float* bd    = (const float*)d_in[15];
  float* out = (float*)d_out;

  const int N = in_sizes[0] / 6;
  const int E = in_sizes[1] / 4;
  const int G = out_size;

  const int* src = eidx;
  const int* dst = eidx + E;

  char* ws = (char*)d_ws;
  size_t off = 0;
  auto alloc = [&](size_t bytes) -> char* {
    char* p = ws + off;
    off = (off + bytes + 255) & ~(size_t)255;
    return p;
  };
  __half* h16     = (__half*)alloc((size_t)N * HH * 2);
  ushort* hresb   = (ushort*)alloc((size_t)N * HH * 2);
  ushort* h1b     = (ushort*)alloc((size_t)N * H2 * 2);
  int*    rowptr  = (int*)alloc((size_t)(N + 1) * 4);
  int*    counts  = (int*)alloc((size_t)N * 4);
  int*    rank    = (int*)alloc((size_t)E * 4);
  int*    soff    = (int*)alloc((size_t)E * 4);
  float4* eattrs  = (float4*)alloc((size_t)E * 16);
  float*  partial = (float*)alloc((size_t)2 * MMP * 256 * 4);
  float*  bnsc    = (float*)alloc(256 * 4);
  float*  bnsh    = (float*)alloc(256 * 4);
  float*  pool    = (float*)alloc((size_t)G * HH * 4);
  float*  cntf    = (float*)alloc((size_t)G * 4);
  short*  w1f     = (short*)alloc((size_t)3 * HH * H2 * 2);
  short*  w2f     = (short*)alloc((size_t)3 * H2 * HH * 2);

  (void)ws_size; (void)n_in;

  hipMemsetAsync(counts, 0, (size_t)N * 4, stream);
  hipMemsetAsync(pool, 0, (size_t)G * HH * 4, stream);

  // weight pre-convert to fragment-major bf16 (all 3 layers)
  k_wconv<<<dim3(128, 3), 256, 0, stream>>>(cw1, w1f, 8, HH);   // [128][256]
  k_wconv<<<dim3(128, 3), 256, 0, stream>>>(cw2, w2f, 7, H2);   // [256][128]

  k_encode<<<(N + 1) / 2, 256, 0, stream>>>(x, wn, bnb, h16, N);
  k_hist<<<(E + 255) / 256, 256, 0, stream>>>(dst, counts, rank, E);
  k_cntg<<<1, 1024, 0, stream>>>(batch, cntf, N, G);
  k_scan<<<1, 1024, 0, stream>>>(counts, rowptr, N);
  k_fill<<<(E + 255) / 256, 256, 0, stream>>>(src, dst, (const float4*)eattr,
                                              rowptr, rank, soff, eattrs, E);

  int mtiles = (N + 63) / 64;
  for (int layer = 0; layer < 3; ++layer) {
    const short* w1 = w1f + (size_t)layer * HH * H2;
    const float* b1 = cb1 + (size_t)layer * H2;
    const float* g_ = cg + (size_t)layer * H2;
    const float* bt = cbt + (size_t)layer * H2;
    const short* w2 = w2f + (size_t)layer * H2 * HH;
    const float* b2 = cb2 + (size_t)layer * HH;

    k_conv<<<(N + 3) / 4, 256, 0, stream>>>(h16, eattrs, we, be, rowptr, soff, hresb, N);
    k_mm1p<<<dim3(MMP, 2), 256, 0, stream>>>(hresb, w1, b1, h1b, partial, N, mtiles);
    k_bnfin<<<16, 256, 0, stream>>>(partial, g_, bt, bnsc, bnsh, 1.f / (float)N);
    k_mm2f<<<mtiles, 256, 0, stream>>>(h1b, w2, b2, bnsc, bnsh, h16, N);
  }

  k_pool<<<(N + 63) / 64, 128, 0, stream>>>(h16, batch, pool, N);
  k_final<<<G, 64, 0, stream>>>(pool, cntf, wd, bd, out);
}

// Round 14
// 479.568 us; speedup vs baseline: 1.0413x; 1.0413x over previous
//
#include <hip/hip_runtime.h>
#include <hip/hip_fp16.h>

// ---------------------------------------------------------------------------
// GENConv GNN forward. Round 14 == Round 13 resubmit (prior bench hit a GPU
// acquisition timeout; no counters were produced).
//  - conv/fill reverted to measured-best round-9 version (48.7 us, VGPR 32);
//    round-10's 8-wide unroll regressed (VGPR 40, occ 47%, 51 us).
//  - k_front: hist + encode + wconv1 + wconv2 merged into one block-range
//    partitioned kernel (hist is atomic-LATENCY bound at 37% occ, 0.2% VALU;
//    encode/wconv blocks give the scheduler work to hide the RMW latency).
//  - parallel 16-block bnfin kept from round 10/12.
// ---------------------------------------------------------------------------

#define HH 128   // hidden
#define H2 256   // 2*hidden
#define MMP 256  // persistent mm1 x-grid

typedef __attribute__((ext_vector_type(8))) short short8v;
typedef __attribute__((ext_vector_type(4))) float f32x4;
typedef __attribute__((ext_vector_type(2))) float f32x2;

__device__ __forceinline__ short f2bf(float f) {
  union { float f; unsigned u; } v; v.f = f;
  unsigned r = v.u + 0x7fff + ((v.u >> 16) & 1);  // round-to-nearest-even
  return (short)(r >> 16);
}
__device__ __forceinline__ float bf2f(ushort s) {
  union { unsigned u; float f; } v; v.u = ((unsigned)s) << 16;
  return v.f;
}
__device__ __forceinline__ f32x2 splat2(float s) { return (f32x2){s, s}; }

// ---- weight convert helper: one element, fp32 [K][Ncols] -> bf16 frag-major
__device__ __forceinline__ void wconv_one(const float* __restrict__ W,
                                          short* __restrict__ out,
                                          int logn, int K, int e) {
  int total = K << logn;                 // 32768 for both weight shapes
  int layer = e >> 15;
  int i = e & (total - 1);
  const float* Wl = W + (size_t)layer * total;
  short* ol = out + (size_t)layer * total;
  int k = i >> logn, col = i & ((1 << logn) - 1);
  int ty = col >> 7, colL = col & 127;
  int wc = colL >> 6, n = (colL >> 4) & 3, l15 = colL & 15;
  int kc = k >> 7, kl = k & 127;
  int ksl = kl >> 5, lhi = (kl >> 3) & 3, j = kl & 7;
  int KC = K >> 7;
  size_t idx = (size_t)(ty * KC + kc) * 16384 +
               ((((wc * 4 + n) * 4 + ksl) * 64 + lhi * 16 + l15) * 8 + j);
  ol[idx] = f2bf(Wl[i]);
}

// ---- merged front-end: [hist | encode | wconv1 | wconv2] by block range ----
__global__ __launch_bounds__(256) void k_front(
    const float* __restrict__ x, const float* __restrict__ wn,
    const float* __restrict__ bnb, __half* __restrict__ h16, int N,
    const int* __restrict__ dst, int* __restrict__ counts,
    int* __restrict__ rank, int E,
    const float* __restrict__ cw1, short* __restrict__ w1f,
    const float* __restrict__ cw2, short* __restrict__ w2f,
    int HB, int EB) {
  int b = blockIdx.x;
  int t = threadIdx.x;
  if (b < HB) {
    int e = b * 256 + t;
    if (e < E) rank[e] = atomicAdd(&counts[dst[e]], 1);
  } else if (b < HB + EB) {
    int bb = b - HB;
    int c = t & 127;
    int node = bb * 2 + (t >> 7);
    if (node < N) {
      const float* xr = x + (size_t)node * 6;
      float acc = bnb[c];
#pragma unroll
      for (int k = 0; k < 6; ++k) acc = fmaf(xr[k], wn[k * HH + c], acc);
      h16[(size_t)node * HH + c] = __float2half(acc);
    }
  } else if (b < HB + EB + 384) {
    int e = (b - HB - EB) * 256 + t;       // 0..98303
    wconv_one(cw1, w1f, 8, HH, e);
  } else {
    int e = (b - HB - EB - 384) * 256 + t; // 0..98303
    wconv_one(cw2, w2f, 7, H2, e);
  }
}

// ---- per-graph node counts via binary search on sorted batch ----
__global__ __launch_bounds__(1024) void k_cntg(const int* __restrict__ batch,
                                               float* __restrict__ cntf, int n, int G) {
  __shared__ int lb[513];
  int t = threadIdx.x;
  for (int v = t; v <= G; v += 1024) {
    int lo = 0, hi = n;
    while (lo < hi) {
      int mid = (lo + hi) >> 1;
      if (batch[mid] < v) lo = mid + 1; else hi = mid;
    }
    lb[v] = lo;
  }
  __syncthreads();
  for (int g = t; g < G; g += 1024) cntf[g] = (float)(lb[g + 1] - lb[g]);
}

// single-block exclusive scan, 4 elements/thread per pass (int4)
__global__ void k_scan(const int* __restrict__ counts, int* __restrict__ rowptr, int n) {
  __shared__ int wsum[16];
  __shared__ int carry;
  int t = threadIdx.x;
  int lane = t & 63, w = t >> 6;
  if (t == 0) carry = 0;
  __syncthreads();
  for (int base = 0; base < n; base += 4096) {
    int idx = base + t * 4;
    int4 v = make_int4(0, 0, 0, 0);
    if (idx + 3 < n) {
      v = *(const int4*)(counts + idx);
    } else {
      if (idx < n)     v.x = counts[idx];
      if (idx + 1 < n) v.y = counts[idx + 1];
      if (idx + 2 < n) v.z = counts[idx + 2];
    }
    int tsum = v.x + v.y + v.z + v.w;
    int x = tsum;
#pragma unroll
    for (int d = 1; d < 64; d <<= 1) {
      int y = __shfl_up(x, d);
      if (lane >= d) x += y;
    }
    if (lane == 63) wsum[w] = x;
    __syncthreads();
    if (w == 0 && lane < 16) {
      int s = wsum[lane];
#pragma unroll
      for (int d = 1; d < 16; d <<= 1) {
        int y = __shfl_up(s, d);
        if (lane >= d) s += y;
      }
      wsum[lane] = s;
    }
    __syncthreads();
    int waveoff = (w == 0) ? 0 : wsum[w - 1];
    int c0 = carry;
    int excl = c0 + waveoff + x - tsum;
    int4 o;
    o.x = excl;
    o.y = excl + v.x;
    o.z = o.y + v.y;
    o.w = o.z + v.z;
    if (idx + 3 < n) {
      *(int4*)(rowptr + idx) = o;
    } else {
      if (idx < n)     rowptr[idx] = o.x;
      if (idx + 1 < n) rowptr[idx + 1] = o.y;
      if (idx + 2 < n) rowptr[idx + 2] = o.z;
    }
    __syncthreads();
    if (t == 0) carry = c0 + wsum[15];
    __syncthreads();
  }
  if (t == 0) rowptr[n] = carry;
}

// scatter edges into CSR order (atomic-free: pos = rowptr[dst] + rank)
__global__ void k_fill(const int* __restrict__ src, const int* __restrict__ dst,
                       const float4* __restrict__ eattr,
                       const int* __restrict__ rowptr, const int* __restrict__ rank,
                       int* __restrict__ ssrc, float4* __restrict__ eattrs, int E) {
  int e = blockIdx.x * 256 + threadIdx.x;
  if (e >= E) return;
  int pos = rowptr[dst[e]] + rank[e];
  ssrc[pos] = src[e];
  eattrs[pos] = eattr[e];
}

// ---- GENConv message + softmax aggregation over CSR ----
// one wave per dst node; lane = 2 channels, packed-fp32 math, 4-deep unroll.
// [round-9 measured-best version: 48.7 us, VGPR 32]
__global__ __launch_bounds__(256) void k_conv(
    const __half* __restrict__ h16, const float4* __restrict__ eattrs,
    const float* __restrict__ we, const float* __restrict__ be,
    const int* __restrict__ rowptr, const int* __restrict__ ssrc,
    ushort* __restrict__ hresb, int n) {
  int d = blockIdx.x * 4 + (threadIdx.x >> 6);
  if (d >= n) return;
  int lane = threadIdx.x & 63;
  int c0 = lane * 2;
  f32x2 W0 = *(const f32x2*)(we + c0);
  f32x2 W1 = *(const f32x2*)(we + 128 + c0);
  f32x2 W2 = *(const f32x2*)(we + 256 + c0);
  f32x2 W3 = *(const f32x2*)(we + 384 + c0);
  f32x2 BE = *(const f32x2*)(be + c0);
  const f32x2 ZERO = splat2(0.f);
  const f32x2 EPS = splat2(1e-7f);
  int p0 = rowptr[d], p1 = rowptr[d + 1];
  f32x2 Sab = ZERO, Wab = ZERO, Scd = ZERO, Wcd = ZERO;
  int p = p0;
  for (; p + 4 <= p1; p += 4) {
    int sA = ssrc[p], sB = ssrc[p + 1], sC = ssrc[p + 2], sD = ssrc[p + 3];
    float4 aA = eattrs[p], aB = eattrs[p + 1], aC = eattrs[p + 2], aD = eattrs[p + 3];
    __half2 hA2 = *(const __half2*)(h16 + (size_t)sA * HH + c0);
    __half2 hB2 = *(const __half2*)(h16 + (size_t)sB * HH + c0);
    __half2 hC2 = *(const __half2*)(h16 + (size_t)sC * HH + c0);
    __half2 hD2 = *(const __half2*)(h16 + (size_t)sD * HH + c0);
    float2 hA = __half22float2(hA2), hB = __half22float2(hB2);
    float2 hC = __half22float2(hC2), hD = __half22float2(hD2);
    f32x2 eA = W0 * splat2(aA.x) + (W1 * splat2(aA.y) + (W2 * splat2(aA.z) + (W3 * splat2(aA.w) + BE)));
    f32x2 eB = W0 * splat2(aB.x) + (W1 * splat2(aB.y) + (W2 * splat2(aB.z) + (W3 * splat2(aB.w) + BE)));
    f32x2 eC = W0 * splat2(aC.x) + (W1 * splat2(aC.y) + (W2 * splat2(aC.z) + (W3 * splat2(aC.w) + BE)));
    f32x2 eD = W0 * splat2(aD.x) + (W1 * splat2(aD.y) + (W2 * splat2(aD.z) + (W3 * splat2(aD.w) + BE)));
    f32x2 mA = __builtin_elementwise_max((f32x2){hA.x, hA.y} + eA, ZERO) + EPS;
    f32x2 mB = __builtin_elementwise_max((f32x2){hB.x, hB.y} + eB, ZERO) + EPS;
    f32x2 mC = __builtin_elementwise_max((f32x2){hC.x, hC.y} + eC, ZERO) + EPS;
    f32x2 mD = __builtin_elementwise_max((f32x2){hD.x, hD.y} + eD, ZERO) + EPS;
    f32x2 xA = (f32x2){__expf(mA.x), __expf(mA.y)};
    f32x2 xB = (f32x2){__expf(mB.x), __expf(mB.y)};
    f32x2 xC = (f32x2){__expf(mC.x), __expf(mC.y)};
    f32x2 xD = (f32x2){__expf(mD.x), __expf(mD.y)};
    Sab += xA + xB;
    Scd += xC + xD;
    Wab += mA * xA + mB * xB;
    Wcd += mC * xC + mD * xD;
  }
  for (; p < p1; ++p) {
    int s = ssrc[p];
    float4 a = eattrs[p];
    __half2 hv2 = *(const __half2*)(h16 + (size_t)s * HH + c0);
    float2 hv = __half22float2(hv2);
    f32x2 e = W0 * splat2(a.x) + (W1 * splat2(a.y) + (W2 * splat2(a.z) + (W3 * splat2(a.w) + BE)));
    f32x2 m = __builtin_elementwise_max((f32x2){hv.x, hv.y} + e, ZERO) + EPS;
    f32x2 xe = (f32x2){__expf(m.x), __expf(m.y)};
    Sab += xe;
    Wab += m * xe;
  }
  f32x2 S = Sab + Scd, W = Wab + Wcd;
  __half2 hd2 = *(const __half2*)(h16 + (size_t)d * HH + c0);
  float2 hd = __half22float2(hd2);
  float r0 = W.x / (S.x + 1e-16f) + hd.x;
  float r1 = W.y / (S.y + 1e-16f) + hd.y;
  ushort2 o;
  o.x = (ushort)f2bf(r0);
  o.y = (ushort)f2bf(r1);
  *(ushort2*)(hresb + (size_t)d * HH + c0) = o;
}

// ---- mm1 (MFMA, persistent): h1b = bf16(hresb @ w1 + b1), BN partials ----
__global__ __launch_bounds__(256) void k_mm1p(
    const ushort* __restrict__ Ab, const short* __restrict__ Bf,
    const float* __restrict__ bias, ushort* __restrict__ Cb,
    float* __restrict__ partial, int M, int mtiles) {
  __shared__ float red[256];
  int t = threadIdx.x;
  int bx = blockIdx.x, ty = blockIdx.y;
  int lane = t & 63, w = t >> 6;
  int wr = w >> 1, wc = w & 1;
  int l15 = lane & 15, lhi = lane >> 4;
  const short* Bt = Bf + (size_t)ty * 16384;
  short8v breg[4][4];
#pragma unroll
  for (int n = 0; n < 4; ++n)
#pragma unroll
    for (int ksl = 0; ksl < 4; ++ksl)
      breg[n][ksl] = *(const short8v*)(Bt + ((((wc * 4 + n) * 4 + ksl) * 64 + lane) * 8));
  float bb[4];
#pragma unroll
  for (int n = 0; n < 4; ++n) bb[n] = bias[ty * 128 + wc * 64 + n * 16 + l15];
  float cs[4] = {0.f, 0.f, 0.f, 0.f}, cq[4] = {0.f, 0.f, 0.f, 0.f};

  short8v a_cur[2][4], a_nxt[2][4];
  int tile = bx;
  if (tile < mtiles) {
    int row0 = tile * 64;
#pragma unroll
    for (int m = 0; m < 2; ++m) {
      int grow = row0 + (wr * 2 + m) * 16 + l15;
      if (grow < M) {
        const ushort* ap = Ab + (size_t)grow * HH + lhi * 8;
#pragma unroll
        for (int ksl = 0; ksl < 4; ++ksl) a_cur[m][ksl] = *(const short8v*)(ap + ksl * 32);
      } else {
#pragma unroll
        for (int ksl = 0; ksl < 4; ++ksl) a_cur[m][ksl] = (short8v){0,0,0,0,0,0,0,0};
      }
    }
  }
#pragma unroll 1
  for (; tile < mtiles; tile += MMP) {
    int nt = tile + MMP;
    if (nt < mtiles) {
      int row0n = nt * 64;
#pragma unroll
      for (int m = 0; m < 2; ++m) {
        int grow = row0n + (wr * 2 + m) * 16 + l15;
        if (grow < M) {
          const ushort* ap = Ab + (size_t)grow * HH + lhi * 8;
#pragma unroll
          for (int ksl = 0; ksl < 4; ++ksl) a_nxt[m][ksl] = *(const short8v*)(ap + ksl * 32);
        } else {
#pragma unroll
          for (int ksl = 0; ksl < 4; ++ksl) a_nxt[m][ksl] = (short8v){0,0,0,0,0,0,0,0};
        }
      }
    }
    f32x4 acc[2][4];
#pragma unroll
    for (int m = 0; m < 2; ++m)
#pragma unroll
      for (int n = 0; n < 4; ++n) acc[m][n] = (f32x4){0.f, 0.f, 0.f, 0.f};
#pragma unroll
    for (int ksl = 0; ksl < 4; ++ksl)
#pragma unroll
      for (int m = 0; m < 2; ++m)
#pragma unroll
        for (int n = 0; n < 4; ++n)
          acc[m][n] = __builtin_amdgcn_mfma_f32_16x16x32_bf16(a_cur[m][ksl], breg[n][ksl],
                                                              acc[m][n], 0, 0, 0);
    int row0 = tile * 64;
#pragma unroll
    for (int n = 0; n < 4; ++n) {
      int colL = wc * 64 + n * 16 + l15;
#pragma unroll
      for (int m = 0; m < 2; ++m) {
        int rbase = row0 + wr * 32 + m * 16 + lhi * 4;
#pragma unroll
        for (int r = 0; r < 4; ++r) {
          int row = rbase + r;
          if (row < M) {
            float o = acc[m][n][r] + bb[n];
            Cb[(size_t)row * H2 + ty * 128 + colL] = (ushort)f2bf(o);
            cs[n] += o; cq[n] += o * o;
          }
        }
      }
    }
#pragma unroll
    for (int m = 0; m < 2; ++m)
#pragma unroll
      for (int ksl = 0; ksl < 4; ++ksl) a_cur[m][ksl] = a_nxt[m][ksl];
  }
  red[t] = 0.f;
  __syncthreads();
#pragma unroll
  for (int n = 0; n < 4; ++n) {
    int colL = wc * 64 + n * 16 + l15;
    atomicAdd(&red[colL], cs[n]);
    atomicAdd(&red[128 + colL], cq[n]);
  }
  __syncthreads();
  partial[((size_t)(ty * MMP + bx)) * 256 + t] = red[t];
}

// ---- reduce partials, fold BN stats (parallel: 16 blocks x 16 channels) ----
__global__ __launch_bounds__(256) void k_bnfin(
    const float* __restrict__ partial, const float* __restrict__ g,
    const float* __restrict__ bt, float* __restrict__ scale,
    float* __restrict__ shift, float invN) {
  __shared__ float shs[256], shq[256];
  int t = threadIdx.x;
  int b = blockIdx.x;          // 0..15
  int ty = b >> 3;             // 0..1
  int col0 = (b & 7) * 16;     // 0..112
  int ch = t & 15;
  int seg = t >> 4;            // 0..15 (each covers 16 partial blocks)
  int colL = col0 + ch;
  const float* base = partial + (size_t)ty * MMP * 256;
  float s = 0.f, q = 0.f;
#pragma unroll 4
  for (int bx = seg * 16; bx < seg * 16 + 16; ++bx) {
    s += base[(size_t)bx * 256 + colL];
    q += base[(size_t)bx * 256 + 128 + colL];
  }
  shs[t] = s; shq[t] = q;
  __syncthreads();
  if (t < 16) {
    float ss = 0.f, qq = 0.f;
#pragma unroll
    for (int sg = 0; sg < 16; ++sg) {
      ss += shs[sg * 16 + t];
      qq += shq[sg * 16 + t];
    }
    int cg = ty * 128 + col0 + t;
    float mu = ss * invN;
    float var = qq * invN - mu * mu;
    float rs = rsqrtf(var + 1e-5f);
    float sc = rs * g[cg];
    scale[cg] = sc;
    shift[cg] = bt[cg] - mu * sc;
  }
}

// ---- mm2 (MFMA): h16 = fp16( relu( relu(h1b*sc+sh) @ w2 + b2 ) ) ----
__global__ __launch_bounds__(256) void k_mm2f(
    const ushort* __restrict__ Ab, const short* __restrict__ Bf,
    const float* __restrict__ bias, const float* __restrict__ scale,
    const float* __restrict__ shift, __half* __restrict__ h16, int M) {
  int t = threadIdx.x;
  int row0 = blockIdx.x * 64;
  int lane = t & 63, w = t >> 6;
  int wr = w >> 1, wc = w & 1;
  int l15 = lane & 15, lhi = lane >> 4;
  int grow[2]; bool gv[2];
#pragma unroll
  for (int m = 0; m < 2; ++m) {
    grow[m] = row0 + (wr * 2 + m) * 16 + l15;
    gv[m] = grow[m] < M;
  }
  f32x4 acc[2][4];
#pragma unroll
  for (int m = 0; m < 2; ++m)
#pragma unroll
    for (int n = 0; n < 4; ++n) acc[m][n] = (f32x4){0.f, 0.f, 0.f, 0.f};
#pragma unroll 1
  for (int kc = 0; kc < 2; ++kc) {
    const short* Bk = Bf + (size_t)kc * 16384;
    short8v breg[4][4];
#pragma unroll
    for (int n = 0; n < 4; ++n)
#pragma unroll
      for (int ksl = 0; ksl < 4; ++ksl)
        breg[n][ksl] = *(const short8v*)(Bk + ((((wc * 4 + n) * 4 + ksl) * 64 + lane) * 8));
#pragma unroll
    for (int ksl = 0; ksl < 4; ++ksl) {
      int kb = kc * 128 + (ksl * 4 + lhi) * 8;
      float4 sc0 = *(const float4*)(scale + kb);
      float4 sc1 = *(const float4*)(scale + kb + 4);
      float4 sh0 = *(const float4*)(shift + kb);
      float4 sh1 = *(const float4*)(shift + kb + 4);
      short8v av[2];
#pragma unroll
      for (int m = 0; m < 2; ++m) {
        if (gv[m]) {
          short8v raw = *(const short8v*)(Ab + (size_t)grow[m] * H2 + kb);
          float f;
          f = fmaxf(fmaf(bf2f((ushort)raw[0]), sc0.x, sh0.x), 0.f); av[m][0] = f2bf(f);
          f = fmaxf(fmaf(bf2f((ushort)raw[1]), sc0.y, sh0.y), 0.f); av[m][1] = f2bf(f);
          f = fmaxf(fmaf(bf2f((ushort)raw[2]), sc0.z, sh0.z), 0.f); av[m][2] = f2bf(f);
          f = fmaxf(fmaf(bf2f((ushort)raw[3]), sc0.w, sh0.w), 0.f); av[m][3] = f2bf(f);
          f = fmaxf(fmaf(bf2f((ushort)raw[4]), sc1.x, sh1.x), 0.f); av[m][4] = f2bf(f);
          f = fmaxf(fmaf(bf2f((ushort)raw[5]), sc1.y, sh1.y), 0.f); av[m][5] = f2bf(f);
          f = fmaxf(fmaf(bf2f((ushort)raw[6]), sc1.z, sh1.z), 0.f); av[m][6] = f2bf(f);
          f = fmaxf(fmaf(bf2f((ushort)raw[7]), sc1.w, sh1.w), 0.f); av[m][7] = f2bf(f);
        } else {
          av[m] = (short8v){0,0,0,0,0,0,0,0};
        }
      }
#pragma unroll
      for (int m = 0; m < 2; ++m)
#pragma unroll
        for (int n = 0; n < 4; ++n)
          acc[m][n] = __builtin_amdgcn_mfma_f32_16x16x32_bf16(av[m], breg[n][ksl],
                                                              acc[m][n], 0, 0, 0);
    }
  }
#pragma unroll
  for (int n = 0; n < 4; ++n) {
    int colL = wc * 64 + n * 16 + l15;
    float bb = bias[colL];
#pragma unroll
    for (int m = 0; m < 2; ++m) {
      int rbase = row0 + wr * 32 + m * 16 + lhi * 4;
#pragma unroll
      for (int r = 0; r < 4; ++r) {
        int row = rbase + r;
        if (row < M)
          h16[(size_t)row * HH + colL] = __float2half(fmaxf(acc[m][n][r] + bb, 0.f));
      }
    }
  }
}

// ---- mean-pool partial sums (batch sorted -> run-length accumulate) ----
__global__ __launch_bounds__(128) void k_pool(const __half* __restrict__ h16,
                                              const int* __restrict__ batch,
                                              float* __restrict__ pool, int n) {
  int c = threadIdx.x;
  int n0 = blockIdx.x * 64;
  int nend = min(n0 + 64, n);
  float acc = 0.f;
  int gprev = batch[n0];
  for (int i = n0; i < nend; ++i) {
    int g = batch[i];
    if (g != gprev) {
      atomicAdd(&pool[(size_t)gprev * HH + c], acc);
      acc = 0.f;
      gprev = g;
    }
    acc += __half2float(h16[(size_t)i * HH + c]);
  }
  atomicAdd(&pool[(size_t)gprev * HH + c], acc);
}

// ---- final: sigmoid(mean_pool @ wd + bd) ----
__global__ __launch_bounds__(64) void k_final(const float* __restrict__ pool,
                                              const float* __restrict__ cntf,
                                              const float* __restrict__ wd,
                                              const float* __restrict__ bd,
                                              float* __restrict__ out) {
  int g = blockIdx.x;
  int t = threadIdx.x;
  float inv = 1.f / fmaxf(cntf[g], 1.f);
  float v = pool[(size_t)g * HH + t] * inv * wd[t] +
            pool[(size_t)g * HH + 64 + t] * inv * wd[64 + t];
#pragma unroll
  for (int d = 32; d; d >>= 1) v += __shfl_down(v, d);
  if (t == 0) out[g] = 1.f / (1.f + __expf(-(v + bd[0])));
}

// ---------------------------------------------------------------------------
extern "C" void kernel_launch(void* const* d_in, const int* in_sizes, int n_in,
                              void* d_out, int out_size, void* d_ws, size_t ws_size,
                              hipStream_t stream) {
  const float* x     = (const float*)d_in[0];
  const float* eattr = (const float*)d_in[1];
  const int*   eidx  = (const int*)d_in[2];
  const int*   batch = (const int*)d_in[3];
  const float* wn    = (const float*)d_in[4];
  const float* bnb   = (const float*)d_in[5];
  const float* we    = (const float*)d_in[6];
  const float* be    = (const float*)d_in[7];
  const float* cw1   = (const float*)d_in[8];
  const float* cb1   = (const float*)d_in[9];
  const float* cg    = (const float*)d_in[10];
  const float* cbt   = (const float*)d_in[11];
  const float* cw2   = (const float*)d_in[12];
  const float* cb2   = (const float*)d_in[13];
  const float* wd    = (const float*)d_in[14];
  const float* bd    = (const float*)d_in[15];
  float* out = (float*)d_out;

  const int N = in_sizes[0] / 6;
  const int E = in_sizes[1] / 4;
  const int G = out_size;

  const int* src = eidx;
  const int* dst = eidx + E;

  char* ws = (char*)d_ws;
  size_t off = 0;
  auto alloc = [&](size_t bytes) -> char* {
    char* p = ws + off;
    off = (off + bytes + 255) & ~(size_t)255;
    return p;
  };
  __half* h16     = (__half*)alloc((size_t)N * HH * 2);
  ushort* hresb   = (ushort*)alloc((size_t)N * HH * 2);
  ushort* h1b     = (ushort*)alloc((size_t)N * H2 * 2);
  int*    rowptr  = (int*)alloc((size_t)(N + 1) * 4);
  int*    counts  = (int*)alloc((size_t)N * 4);
  int*    rank    = (int*)alloc((size_t)E * 4);
  int*    ssrc    = (int*)alloc((size_t)E * 4);
  float4* eattrs  = (float4*)alloc((size_t)E * 16);
  float*  partial = (float*)alloc((size_t)2 * MMP * 256 * 4);
  float*  bnsc    = (float*)alloc(256 * 4);
  float*  bnsh    = (float*)alloc(256 * 4);
  float*  pool    = (float*)alloc((size_t)G * HH * 4);
  float*  cntf    = (float*)alloc((size_t)G * 4);
  short*  w1f     = (short*)alloc((size_t)3 * HH * H2 * 2);
  short*  w2f     = (short*)alloc((size_t)3 * H2 * HH * 2);

  (void)ws_size; (void)n_in;

  hipMemsetAsync(counts, 0, (size_t)N * 4, stream);
  hipMemsetAsync(pool, 0, (size_t)G * HH * 4, stream);

  // merged front-end: hist | encode | wconv1 | wconv2
  int HB = (E + 255) / 256;
  int EB = (N + 1) / 2;
  k_front<<<HB + EB + 768, 256, 0, stream>>>(x, wn, bnb, h16, N,
                                             dst, counts, rank, E,
                                             cw1, w1f, cw2, w2f, HB, EB);
  k_cntg<<<1, 1024, 0, stream>>>(batch, cntf, N, G);
  k_scan<<<1, 1024, 0, stream>>>(counts, rowptr, N);
  k_fill<<<(E + 255) / 256, 256, 0, stream>>>(src, dst, (const float4*)eattr,
                                              rowptr, rank, ssrc, eattrs, E);

  int mtiles = (N + 63) / 64;
  for (int layer = 0; layer < 3; ++layer) {
    const short* w1 = w1f + (size_t)layer * HH * H2;
    const float* b1 = cb1 + (size_t)layer * H2;
    const float* g_ = cg + (size_t)layer * H2;
    const float* bt = cbt + (size_t)layer * H2;
    const short* w2 = w2f + (size_t)layer * H2 * HH;
    const float* b2 = cb2 + (size_t)layer * HH;

    k_conv<<<(N + 3) / 4, 256, 0, stream>>>(h16, eattrs, we, be, rowptr, ssrc, hresb, N);
    k_mm1p<<<dim3(MMP, 2), 256, 0, stream>>>(hresb, w1, b1, h1b, partial, N, mtiles);
    k_bnfin<<<16, 256, 0, stream>>>(partial, g_, bt, bnsc, bnsh, 1.f / (float)N);
    k_mm2f<<<mtiles, 256, 0, stream>>>(h1b, w2, b2, bnsc, bnsh, h16, N);
  }

  k_pool<<<(N + 63) / 64, 128, 0, stream>>>(h16, batch, pool, N);
  k_final<<<G, 64, 0, stream>>>(pool, cntf, wd, bd, out);
}